// Round 8
// baseline (565.440 us; speedup 1.0000x reference)
//
#include <hip/hip_runtime.h>

typedef __attribute__((ext_vector_type(8))) short short8;
typedef __attribute__((ext_vector_type(4))) float floatx4;

// ---- bf16 split helpers (round-to-nearest-even) ----
static __device__ __forceinline__ unsigned short f2bf(float f) {
    unsigned u = __float_as_uint(f);
    u += 0x7fff + ((u >> 16) & 1);
    return (unsigned short)(u >> 16);
}
static __device__ __forceinline__ float bf2f(unsigned short h) {
    return __uint_as_float((unsigned)h << 16);
}
static __device__ __forceinline__ unsigned packsplit(float f) {
    unsigned short hi = f2bf(f);
    unsigned short lo = f2bf(f - bf2f(hi));
    return ((unsigned)hi << 16) | lo;
}

// ---------------- CSR build ----------------

__global__ void init_kernel(int* degi, int n) {
    int i = blockIdx.x * 256 + threadIdx.x;
    if (i < n) degi[i] = 1;              // self-loop
}

__global__ void count_kernel(const int* __restrict__ ei, int* degi, int E) {
    int e = blockIdx.x * 256 + threadIdx.x;
    if (e < E) atomicAdd(&degi[ei[E + e]], 1);   // col = dest
}

__global__ __launch_bounds__(256) void scan_bsum_kernel(const int* __restrict__ degi,
                                                        float* __restrict__ dinv,
                                                        int* bsum, int n) {
    int tid = threadIdx.x;
    int i = blockIdx.x * 256 + tid;
    int v = (i < n) ? degi[i] : 0;
    if (i < n) dinv[i] = rsqrtf((float)v);
    #pragma unroll
    for (int off = 32; off > 0; off >>= 1) v += __shfl_down(v, off);
    __shared__ int ws[4];
    if ((tid & 63) == 0) ws[tid >> 6] = v;
    __syncthreads();
    if (tid == 0) bsum[blockIdx.x] = ws[0] + ws[1] + ws[2] + ws[3];
}

__global__ __launch_bounds__(256) void scan_sums_kernel(const int* __restrict__ bsum,
                                                        int* boff, int nb) {
    int tid = threadIdx.x;
    int v = (tid < nb) ? bsum[tid] : 0;
    int lane = tid & 63, wid = tid >> 6;
    int x = v;
    #pragma unroll
    for (int off = 1; off < 64; off <<= 1) {
        int y = __shfl_up(x, off);
        if (lane >= off) x += y;
    }
    __shared__ int ws[4];
    if (lane == 63) ws[wid] = x;
    __syncthreads();
    if (tid == 0) { int a = 0; for (int j = 0; j < 4; ++j) { int t = ws[j]; ws[j] = a; a += t; } }
    __syncthreads();
    if (tid < nb) boff[tid] = x - v + ws[wid];
}

__global__ __launch_bounds__(256) void scan_emit_kernel(const int* __restrict__ degi,
                                                        const int* __restrict__ boff,
                                                        int* rp, int* cursor, int n) {
    int tid = threadIdx.x;
    int i = blockIdx.x * 256 + tid;
    int v = (i < n) ? degi[i] : 0;
    int lane = tid & 63, wid = tid >> 6;
    int x = v;
    #pragma unroll
    for (int off = 1; off < 64; off <<= 1) {
        int y = __shfl_up(x, off);
        if (lane >= off) x += y;
    }
    __shared__ int ws[4];
    if (lane == 63) ws[wid] = x;
    __syncthreads();
    if (tid == 0) { int a = 0; for (int j = 0; j < 4; ++j) { int t = ws[j]; ws[j] = a; a += t; } }
    __syncthreads();
    int excl = x - v + ws[wid] + boff[blockIdx.x];
    if (i < n) { rp[i] = excl; cursor[i] = excl; }
    if (i == n - 1) rp[n] = excl + v;
}

__global__ void fill_kernel(const int* __restrict__ ei, const float* __restrict__ dinv,
                            int* cursor, long long* __restrict__ csr, int E, int n) {
    int e = blockIdx.x * 256 + threadIdx.x;
    if (e >= E + n) return;
    int r, c;
    if (e < E) { r = ei[e]; c = ei[E + e]; }
    else       { r = e - E; c = r; }
    int pos = atomicAdd(&cursor[c], 1);
    float wv = dinv[r] * dinv[c];
    long long packed = (long long)(unsigned int)r
                     | ((long long)(unsigned int)__float_as_int(wv) << 32);
    csr[pos] = packed;
}

// ---------------- packing kernels ----------------

// x row-major [n x 128] -> packed slab layout hpS[slab][row][16]
__global__ void packx_kernel(const float* __restrict__ x, unsigned* __restrict__ xp,
                             int n, int total) {
    int i = blockIdx.x * 256 + threadIdx.x;
    if (i < total) {
        int row = i >> 7, ch = i & 127;
        xp[((size_t)(ch >> 4) * n + row) * 16 + (ch & 15)] = packsplit(x[i]);
    }
}

// W[k][n] fp32 -> Wt_hi[n][k], Wt_lo[n][k] bf16, for 6 layers
__global__ void packw_kernel(const float* w0, const float* w1, const float* w2,
                             const float* w3, const float* w4, const float* w5,
                             unsigned short* __restrict__ hi, unsigned short* __restrict__ lo) {
    int l = blockIdx.y;
    const float* W = (l == 0) ? w0 : (l == 1) ? w1 : (l == 2) ? w2
                   : (l == 3) ? w3 : (l == 4) ? w4 : w5;
    int idx = blockIdx.x * 256 + threadIdx.x;   // 0..16383
    int k = idx >> 7, nn = idx & 127;
    float v = W[k * 128 + nn];
    unsigned short h = f2bf(v);
    unsigned short ls = f2bf(v - bf2f(h));
    hi[l * 16384 + nn * 128 + k] = h;
    lo[l * 16384 + nn * 128 + k] = ls;
}

// ---------------- split-bf16 MFMA GEMM (slab layouts) ----------------
// A: packed uint32 slab layout Ap[slab][row][16] (slab = ch>>4).
// Wt_hi/Wt_lo = W^T bf16 [128 n][128 k], staged into LDS once per block.
// C: fp32 slab layout Cs[slab][row][16].
// 512 threads = 8 waves x 16 rows = 128 rows/block.

#define WLDS_STRIDE 260

__global__ __launch_bounds__(512) void gemm_kernel(const unsigned* __restrict__ Ap,
                                                   const unsigned short* __restrict__ Wth,
                                                   const unsigned short* __restrict__ Wtl,
                                                   float* __restrict__ Cs, int n) {
    __shared__ unsigned short Wlds[128 * WLDS_STRIDE];   // 66560 B
    int tid = threadIdx.x;
    #pragma unroll
    for (int it = 0; it < 8; ++it) {
        int c = it * 512 + tid;
        int row = c >> 5, piece = c & 31;
        const unsigned short* src = (piece < 16)
            ? (Wth + (size_t)row * 128 + piece * 8)
            : (Wtl + (size_t)row * 128 + (piece - 16) * 8);
        int dst = row * WLDS_STRIDE + ((piece < 16) ? piece * 8 : 128 + (piece - 16) * 8);
        *(short8*)&Wlds[dst] = *(const short8*)src;
    }

    int wave = tid >> 6;
    int lane = tid & 63;
    int m = lane & 15, quad = lane >> 4;
    int row0 = blockIdx.x * 128 + wave * 16;
    floatx4 acc[8];
    #pragma unroll
    for (int ct = 0; ct < 8; ++ct) acc[ct] = (floatx4){0.f, 0.f, 0.f, 0.f};

    int arow = row0 + m; if (arow > n - 1) arow = n - 1;
    __syncthreads();

    #pragma unroll
    for (int kc = 0; kc < 4; ++kc) {
        // channels k0 = kc*32 + quad*8 .. +7 live in slab (k0>>4), offset (quad&1)*8
        int slab = 2 * kc + (quad >> 1);
        const unsigned* ap = Ap + ((size_t)slab * n + arow) * 16 + (quad & 1) * 8;
        uint4 u0 = *(const uint4*)ap;
        uint4 u1 = *(const uint4*)(ap + 4);
        short8 ah, al;
        ah[0] = (short)(u0.x >> 16); al[0] = (short)(u0.x & 0xffff);
        ah[1] = (short)(u0.y >> 16); al[1] = (short)(u0.y & 0xffff);
        ah[2] = (short)(u0.z >> 16); al[2] = (short)(u0.z & 0xffff);
        ah[3] = (short)(u0.w >> 16); al[3] = (short)(u0.w & 0xffff);
        ah[4] = (short)(u1.x >> 16); al[4] = (short)(u1.x & 0xffff);
        ah[5] = (short)(u1.y >> 16); al[5] = (short)(u1.y & 0xffff);
        ah[6] = (short)(u1.z >> 16); al[6] = (short)(u1.z & 0xffff);
        ah[7] = (short)(u1.w >> 16); al[7] = (short)(u1.w & 0xffff);
        #pragma unroll
        for (int ct = 0; ct < 8; ++ct) {
            int base = (ct * 16 + m) * WLDS_STRIDE + kc * 32 + quad * 8;
            short8 wh = *(const short8*)&Wlds[base];
            short8 wl = *(const short8*)&Wlds[base + 128];
            acc[ct] = __builtin_amdgcn_mfma_f32_16x16x32_bf16(al, wl, acc[ct], 0, 0, 0);
            acc[ct] = __builtin_amdgcn_mfma_f32_16x16x32_bf16(ah, wl, acc[ct], 0, 0, 0);
            acc[ct] = __builtin_amdgcn_mfma_f32_16x16x32_bf16(al, wh, acc[ct], 0, 0, 0);
            acc[ct] = __builtin_amdgcn_mfma_f32_16x16x32_bf16(ah, wh, acc[ct], 0, 0, 0);
        }
    }
    #pragma unroll
    for (int ct = 0; ct < 8; ++ct) {         // ct == output slab
        #pragma unroll
        for (int r = 0; r < 4; ++r) {
            int row = row0 + quad * 4 + r;
            if (row < n) Cs[((size_t)ct * n + row) * 16 + m] = acc[ct][r];
        }
    }
}

// ---------------- aggregation: XCD slab-sliced, LDS-staged edges ----------------
// slice = blockIdx&7 rides round-robin block->XCD dispatch; gathers hit the
// XCD-resident 3.2 MB t-slab. Edge lists cooperatively staged via NT loads.

__global__ __launch_bounds__(256) void agg_kernel(const float* __restrict__ tS,
                                                  const float* __restrict__ bias,
                                                  const int* __restrict__ rp,
                                                  const long long* __restrict__ csr,
                                                  unsigned* __restrict__ hpS, int n) {
    __shared__ long long eL[256];
    int slice = blockIdx.x & 7;
    int chunk = blockIdx.x >> 3;
    int tid = threadIdx.x;
    int lane = tid & 15;
    int g = tid >> 4;                    // node group 0..15
    int jbase = chunk * 16;
    if (jbase >= n) return;
    int j = jbase + g;
    int jcap = jbase + 16; if (jcap > n) jcap = n;
    const float* slab = tS + (size_t)slice * n * 16;
    int pstart = rp[jbase];
    int pend   = rp[jcap];
    bool active = (j < n);
    int p0 = active ? rp[j] : 0;
    int p1 = active ? rp[j + 1] : 0;
    float a0 = 0.f, a1 = 0.f, a2 = 0.f, a3 = 0.f;
    for (int base = pstart; base < pend; base += 256) {
        int cnt = pend - base; if (cnt > 256) cnt = 256;
        __syncthreads();
        if (tid < cnt) eL[tid] = __builtin_nontemporal_load(&csr[base + tid]);
        __syncthreads();
        int lo = p0 > base ? p0 - base : 0;
        int hi = (p1 < base + cnt ? p1 : base + cnt) - base;
        int q = lo;
        for (; q + 4 <= hi; q += 4) {
            long long e0 = eL[q], e1 = eL[q + 1], e2 = eL[q + 2], e3 = eL[q + 3];
            a0 += __int_as_float((int)(e0 >> 32)) * slab[(size_t)(int)e0 * 16 + lane];
            a1 += __int_as_float((int)(e1 >> 32)) * slab[(size_t)(int)e1 * 16 + lane];
            a2 += __int_as_float((int)(e2 >> 32)) * slab[(size_t)(int)e2 * 16 + lane];
            a3 += __int_as_float((int)(e3 >> 32)) * slab[(size_t)(int)e3 * 16 + lane];
        }
        for (; q < hi; ++q) {
            long long e0 = eL[q];
            a0 += __int_as_float((int)(e0 >> 32)) * slab[(size_t)(int)e0 * 16 + lane];
        }
    }
    if (active) {
        float res = a0 + a1 + a2 + a3 + bias[slice * 16 + lane];
        unsigned pk = packsplit(fmaxf(res, 0.f));
        __builtin_nontemporal_store(pk, &hpS[((size_t)slice * n + j) * 16 + lane]);
    }
}

// ---------------- pooling + classifier (slab-layout t, no atomics) ----------------

__global__ __launch_bounds__(256) void pool_kernel(const float* __restrict__ tS,
                                                   const float* __restrict__ bfc,
                                                   const int* __restrict__ batch,
                                                   const float* __restrict__ Wlin,
                                                   const float* __restrict__ blin,
                                                   float* __restrict__ out, int n) {
    int g = blockIdx.x;
    int tid = threadIdx.x;
    int lo = 0, hi = n;
    while (lo < hi) { int m = (lo + hi) >> 1; if (batch[m] < g) lo = m + 1; else hi = m; }
    int start = lo;
    lo = start; hi = n;
    while (lo < hi) { int m = (lo + hi) >> 1; if (batch[m] < g + 1) lo = m + 1; else hi = m; }
    int end = lo;

    int lane = tid & 31, sub = tid >> 5;
    int c4 = lane * 4;
    int slab = c4 >> 4, off = c4 & 15;
    const float* base = tS + (size_t)slab * n * 16;
    float4 bv = *(const float4*)&bfc[c4];
    float sx = 0.f, sy = 0.f, sz = 0.f, sw = 0.f;
    for (int j = start + sub; j < end; j += 8) {
        float4 v = *(const float4*)&base[(size_t)j * 16 + off];
        sx += fmaxf(v.x + bv.x, 0.f);
        sy += fmaxf(v.y + bv.y, 0.f);
        sz += fmaxf(v.z + bv.z, 0.f);
        sw += fmaxf(v.w + bv.w, 0.f);
    }
    __shared__ float red[8][128];
    red[sub][c4] = sx; red[sub][c4 + 1] = sy; red[sub][c4 + 2] = sz; red[sub][c4 + 3] = sw;
    __syncthreads();
    __shared__ float pooled[128];
    if (tid < 128) {
        float s = 0.f;
        #pragma unroll
        for (int k = 0; k < 8; ++k) s += red[k][tid];
        float pv = s / fmaxf((float)(end - start), 1.f);
        pooled[tid] = pv;
        out[1280 + g * 128 + tid] = pv;
    }
    __syncthreads();
    if (tid < 10) {
        float a = blin[tid];
        for (int k = 0; k < 128; ++k) a += pooled[k] * Wlin[k * 10 + tid];
        out[g * 10 + tid] = a;
    }
}

// ---------------- launch ----------------

extern "C" void kernel_launch(void* const* d_in, const int* in_sizes, int n_in,
                              void* d_out, int out_size, void* d_ws, size_t ws_size,
                              hipStream_t stream) {
    const float* x     = (const float*)d_in[0];
    const int*   ei    = (const int*)d_in[1];
    const int*   batch = (const int*)d_in[2];
    const float* Wl[6] = {(const float*)d_in[3], (const float*)d_in[5], (const float*)d_in[7],
                          (const float*)d_in[9], (const float*)d_in[11], (const float*)d_in[13]};
    const float* bl[6] = {(const float*)d_in[4], (const float*)d_in[6], (const float*)d_in[8],
                          (const float*)d_in[10], (const float*)d_in[12], (const float*)d_in[14]};
    const float* Wlin = (const float*)d_in[15];
    const float* blin = (const float*)d_in[16];

    const int N = in_sizes[2];        // 50000
    const int E = in_sizes[1] / 2;    // 600000
    (void)n_in; (void)out_size; (void)ws_size;

    char* p = (char*)d_ws;
    auto carve = [&](size_t bytes) { void* r = (void*)p; p += (bytes + 255) & ~(size_t)255; return r; };
    float*          tS     = (float*)carve((size_t)N * 128 * 4);      // fp32 slabs [8][N][16]
    unsigned*       hpS    = (unsigned*)carve((size_t)N * 128 * 4);   // packed slabs [8][N][16]
    int*            degi   = (int*)carve((size_t)N * 4);
    float*          dinv   = (float*)carve((size_t)N * 4);
    int*            rp     = (int*)carve((size_t)(N + 1) * 4);
    int*            cursor = (int*)carve((size_t)N * 4);
    long long*      csr    = (long long*)carve((size_t)(E + N) * 8);
    int*            bsum   = (int*)carve(256 * 4);
    int*            boff   = (int*)carve(256 * 4);
    unsigned short* wth    = (unsigned short*)carve(6 * 16384 * 2);
    unsigned short* wtl    = (unsigned short*)carve(6 * 16384 * 2);

    int gN = (N + 255) / 256;
    init_kernel<<<gN, 256, 0, stream>>>(degi, N);
    count_kernel<<<(E + 255) / 256, 256, 0, stream>>>(ei, degi, E);
    scan_bsum_kernel<<<gN, 256, 0, stream>>>(degi, dinv, bsum, N);
    scan_sums_kernel<<<1, 256, 0, stream>>>(bsum, boff, gN);
    scan_emit_kernel<<<gN, 256, 0, stream>>>(degi, boff, rp, cursor, N);
    fill_kernel<<<(E + N + 255) / 256, 256, 0, stream>>>(ei, dinv, cursor, csr, E, N);

    packx_kernel<<<(N * 128 + 255) / 256, 256, 0, stream>>>(x, hpS, N, N * 128);
    packw_kernel<<<dim3(64, 6), 256, 0, stream>>>(Wl[0], Wl[1], Wl[2], Wl[3], Wl[4], Wl[5],
                                                  wth, wtl);

    int gGemm = (N + 127) / 128;
    int gAgg  = 8 * ((N + 15) / 16);
    for (int l = 0; l < 5; ++l) {
        gemm_kernel<<<gGemm, 512, 0, stream>>>(hpS, wth + l * 16384, wtl + l * 16384, tS, N);
        agg_kernel<<<gAgg, 256, 0, stream>>>(tS, bl[l], rp, csr, hpS, N);
    }
    gemm_kernel<<<gGemm, 512, 0, stream>>>(hpS, wth + 5 * 16384, wtl + 5 * 16384, tS, N);
    pool_kernel<<<128, 256, 0, stream>>>(tS, bl[5], batch, Wlin, blin, (float*)d_out, N);
}

// Round 9
// 508.669 us; speedup vs baseline: 1.1116x; 1.1116x over previous
//
#include <hip/hip_runtime.h>

typedef __attribute__((ext_vector_type(8))) short short8;
typedef __attribute__((ext_vector_type(4))) float floatx4;

// ---- bf16 split helpers (round-to-nearest-even) ----
static __device__ __forceinline__ unsigned short f2bf(float f) {
    unsigned u = __float_as_uint(f);
    u += 0x7fff + ((u >> 16) & 1);
    return (unsigned short)(u >> 16);
}
static __device__ __forceinline__ float bf2f(unsigned short h) {
    return __uint_as_float((unsigned)h << 16);
}
static __device__ __forceinline__ unsigned packsplit(float f) {
    unsigned short hi = f2bf(f);
    unsigned short lo = f2bf(f - bf2f(hi));
    return ((unsigned)hi << 16) | lo;
}

// ---------------- CSR build (degi memset to 0 by host-side hipMemsetAsync) ----------------

__global__ void count_kernel(const int* __restrict__ ei, int* degi, int E) {
    int e = blockIdx.x * 256 + threadIdx.x;
    if (e < E) atomicAdd(&degi[ei[E + e]], 1);   // col = dest
}

// per-block sums of 256 (deg+1) values, + fused dinv
__global__ __launch_bounds__(256) void scan_bsum_kernel(const int* __restrict__ degi,
                                                        float* __restrict__ dinv,
                                                        int* bsum, int n) {
    int tid = threadIdx.x;
    int i = blockIdx.x * 256 + tid;
    int v = (i < n) ? degi[i] + 1 : 0;           // +1 self-loop
    if (i < n) dinv[i] = rsqrtf((float)v);
    #pragma unroll
    for (int off = 32; off > 0; off >>= 1) v += __shfl_down(v, off);
    __shared__ int ws[4];
    if ((tid & 63) == 0) ws[tid >> 6] = v;
    __syncthreads();
    if (tid == 0) bsum[blockIdx.x] = ws[0] + ws[1] + ws[2] + ws[3];
}

// emit rp/cursor; fused block-offset reduction (no separate scan_sums kernel)
__global__ __launch_bounds__(256) void scan_emit_kernel(const int* __restrict__ degi,
                                                        const int* __restrict__ bsum,
                                                        int* rp, int* cursor, int n, int nb) {
    int tid = threadIdx.x;
    int bid = blockIdx.x;
    // boff = sum of bsum[0..bid)
    int contrib = 0;
    for (int t = tid; t < bid; t += 256) contrib += bsum[t];
    int cr = contrib;
    #pragma unroll
    for (int off = 32; off > 0; off >>= 1) cr += __shfl_down(cr, off);
    __shared__ int wr[4];
    __shared__ int s_boff;
    if ((tid & 63) == 0) wr[tid >> 6] = cr;
    __syncthreads();
    if (tid == 0) s_boff = wr[0] + wr[1] + wr[2] + wr[3];
    __syncthreads();

    int i = bid * 256 + tid;
    int v = (i < n) ? degi[i] + 1 : 0;
    int lane = tid & 63, wid = tid >> 6;
    int x = v;
    #pragma unroll
    for (int off = 1; off < 64; off <<= 1) {
        int y = __shfl_up(x, off);
        if (lane >= off) x += y;
    }
    __shared__ int ws[4];
    if (lane == 63) ws[wid] = x;
    __syncthreads();
    if (tid == 0) { int a = 0; for (int j = 0; j < 4; ++j) { int t = ws[j]; ws[j] = a; a += t; } }
    __syncthreads();
    int excl = x - v + ws[wid] + s_boff;
    if (i < n) { rp[i] = excl; cursor[i] = excl; }
    if (i == n - 1) rp[n] = excl + v;
}

__global__ void fill_kernel(const int* __restrict__ ei, const float* __restrict__ dinv,
                            int* cursor, long long* __restrict__ csr, int E, int n) {
    int e = blockIdx.x * 256 + threadIdx.x;
    if (e >= E + n) return;
    int r, c;
    if (e < E) { r = ei[e]; c = ei[E + e]; }
    else       { r = e - E; c = r; }
    int pos = atomicAdd(&cursor[c], 1);
    float wv = dinv[r] * dinv[c];
    long long packed = (long long)(unsigned int)r
                     | ((long long)(unsigned int)__float_as_int(wv) << 32);
    csr[pos] = packed;
}

// ---------------- weight packing: W[k][n] -> Wt_hi[n][k], Wt_lo[n][k] ----------------

__global__ void packw_kernel(const float* w0, const float* w1, const float* w2,
                             const float* w3, const float* w4, const float* w5,
                             unsigned short* __restrict__ hi, unsigned short* __restrict__ lo) {
    int l = blockIdx.y;
    const float* W = (l == 0) ? w0 : (l == 1) ? w1 : (l == 2) ? w2
                   : (l == 3) ? w3 : (l == 4) ? w4 : w5;
    int idx = blockIdx.x * 256 + threadIdx.x;
    int k = idx >> 7, nn = idx & 127;
    float v = W[k * 128 + nn];
    unsigned short h = f2bf(v);
    unsigned short ls = f2bf(v - bf2f(h));
    hi[l * 16384 + nn * 128 + k] = h;
    lo[l * 16384 + nn * 128 + k] = ls;
}

// ---------------- split-bf16 MFMA GEMM core ----------------
// Wt_hi/Wt_lo staged into LDS (stride 260 shorts: hi[0..127], lo[128..255] per row).
// 512 threads = 8 waves x 16 rows = 128 rows/block.
// Fragments (verified R5): a[j]=A[m=lane&15][k=quad*8+j], D: col=lane&15, row=quad*4+reg.

#define WLDS_STRIDE 260

static __device__ __forceinline__ void stage_w(const unsigned short* __restrict__ Wth,
                                               const unsigned short* __restrict__ Wtl,
                                               unsigned short* Wlds, int tid) {
    #pragma unroll
    for (int it = 0; it < 8; ++it) {
        int c = it * 512 + tid;
        int row = c >> 5, piece = c & 31;
        const unsigned short* src = (piece < 16)
            ? (Wth + (size_t)row * 128 + piece * 8)
            : (Wtl + (size_t)row * 128 + (piece - 16) * 8);
        int dst = row * WLDS_STRIDE + ((piece < 16) ? piece * 8 : 128 + (piece - 16) * 8);
        *(short8*)&Wlds[dst] = *(const short8*)src;
    }
}

static __device__ __forceinline__ void unpack_u(uint4 u0, uint4 u1, short8& ah, short8& al) {
    ah[0] = (short)(u0.x >> 16); al[0] = (short)(u0.x & 0xffff);
    ah[1] = (short)(u0.y >> 16); al[1] = (short)(u0.y & 0xffff);
    ah[2] = (short)(u0.z >> 16); al[2] = (short)(u0.z & 0xffff);
    ah[3] = (short)(u0.w >> 16); al[3] = (short)(u0.w & 0xffff);
    ah[4] = (short)(u1.x >> 16); al[4] = (short)(u1.x & 0xffff);
    ah[5] = (short)(u1.y >> 16); al[5] = (short)(u1.y & 0xffff);
    ah[6] = (short)(u1.z >> 16); al[6] = (short)(u1.z & 0xffff);
    ah[7] = (short)(u1.w >> 16); al[7] = (short)(u1.w & 0xffff);
}

__global__ __launch_bounds__(512) void gemm_kernel(const unsigned* __restrict__ Ap,
                                                   const unsigned short* __restrict__ Wth,
                                                   const unsigned short* __restrict__ Wtl,
                                                   float* __restrict__ C, int n) {
    __shared__ unsigned short Wlds[128 * WLDS_STRIDE];
    int tid = threadIdx.x;
    int wave = tid >> 6, lane = tid & 63;
    int m = lane & 15, quad = lane >> 4;
    int row0 = blockIdx.x * 128 + wave * 16;
    int arow = row0 + m; if (arow > n - 1) arow = n - 1;
    const unsigned* aptr = Ap + (size_t)arow * 128 + quad * 8;

    // prefetch kc=0 A before staging W (overlap global latency with LDS fill)
    uint4 p0 = *(const uint4*)(aptr);
    uint4 p1 = *(const uint4*)(aptr + 4);

    stage_w(Wth, Wtl, Wlds, tid);

    floatx4 acc[8];
    #pragma unroll
    for (int ct = 0; ct < 8; ++ct) acc[ct] = (floatx4){0.f, 0.f, 0.f, 0.f};
    __syncthreads();

    #pragma unroll
    for (int kc = 0; kc < 4; ++kc) {
        uint4 u0, u1;
        if (kc == 0) { u0 = p0; u1 = p1; }
        else { u0 = *(const uint4*)(aptr + kc * 32); u1 = *(const uint4*)(aptr + kc * 32 + 4); }
        short8 ah, al;
        unpack_u(u0, u1, ah, al);
        #pragma unroll
        for (int ct = 0; ct < 8; ++ct) {
            int base = (ct * 16 + m) * WLDS_STRIDE + kc * 32 + quad * 8;
            short8 wh = *(const short8*)&Wlds[base];
            short8 wl = *(const short8*)&Wlds[base + 128];
            acc[ct] = __builtin_amdgcn_mfma_f32_16x16x32_bf16(al, wl, acc[ct], 0, 0, 0);
            acc[ct] = __builtin_amdgcn_mfma_f32_16x16x32_bf16(ah, wl, acc[ct], 0, 0, 0);
            acc[ct] = __builtin_amdgcn_mfma_f32_16x16x32_bf16(al, wh, acc[ct], 0, 0, 0);
            acc[ct] = __builtin_amdgcn_mfma_f32_16x16x32_bf16(ah, wh, acc[ct], 0, 0, 0);
        }
    }
    #pragma unroll
    for (int ct = 0; ct < 8; ++ct) {
        #pragma unroll
        for (int r = 0; r < 4; ++r) {
            int row = row0 + quad * 4 + r;
            if (row < n) C[(size_t)row * 128 + ct * 16 + m] = acc[ct][r];
        }
    }
}

// layer-0 variant: reads fp32 x directly, splits inline (packx kernel eliminated)
__global__ __launch_bounds__(512) void gemm0_kernel(const float* __restrict__ X,
                                                    const unsigned short* __restrict__ Wth,
                                                    const unsigned short* __restrict__ Wtl,
                                                    float* __restrict__ C, int n) {
    __shared__ unsigned short Wlds[128 * WLDS_STRIDE];
    int tid = threadIdx.x;
    int wave = tid >> 6, lane = tid & 63;
    int m = lane & 15, quad = lane >> 4;
    int row0 = blockIdx.x * 128 + wave * 16;
    int arow = row0 + m; if (arow > n - 1) arow = n - 1;
    const float* aptr = X + (size_t)arow * 128 + quad * 8;

    float4 pf0 = *(const float4*)(aptr);
    float4 pf1 = *(const float4*)(aptr + 4);

    stage_w(Wth, Wtl, Wlds, tid);

    floatx4 acc[8];
    #pragma unroll
    for (int ct = 0; ct < 8; ++ct) acc[ct] = (floatx4){0.f, 0.f, 0.f, 0.f};
    __syncthreads();

    #pragma unroll
    for (int kc = 0; kc < 4; ++kc) {
        float4 f0, f1;
        if (kc == 0) { f0 = pf0; f1 = pf1; }
        else { f0 = *(const float4*)(aptr + kc * 32); f1 = *(const float4*)(aptr + kc * 32 + 4); }
        float fv[8] = {f0.x, f0.y, f0.z, f0.w, f1.x, f1.y, f1.z, f1.w};
        short8 ah, al;
        #pragma unroll
        for (int j = 0; j < 8; ++j) {
            unsigned short h = f2bf(fv[j]);
            ah[j] = (short)h;
            al[j] = (short)f2bf(fv[j] - bf2f(h));
        }
        #pragma unroll
        for (int ct = 0; ct < 8; ++ct) {
            int base = (ct * 16 + m) * WLDS_STRIDE + kc * 32 + quad * 8;
            short8 wh = *(const short8*)&Wlds[base];
            short8 wl = *(const short8*)&Wlds[base + 128];
            acc[ct] = __builtin_amdgcn_mfma_f32_16x16x32_bf16(al, wl, acc[ct], 0, 0, 0);
            acc[ct] = __builtin_amdgcn_mfma_f32_16x16x32_bf16(ah, wl, acc[ct], 0, 0, 0);
            acc[ct] = __builtin_amdgcn_mfma_f32_16x16x32_bf16(al, wh, acc[ct], 0, 0, 0);
            acc[ct] = __builtin_amdgcn_mfma_f32_16x16x32_bf16(ah, wh, acc[ct], 0, 0, 0);
        }
    }
    #pragma unroll
    for (int ct = 0; ct < 8; ++ct) {
        #pragma unroll
        for (int r = 0; r < 4; ++r) {
            int row = row0 + quad * 4 + r;
            if (row < n) C[(size_t)row * 128 + ct * 16 + m] = acc[ct][r];
        }
    }
}

// ---------------- aggregation (R5 exact form: plain loads/stores) ----------------

__global__ __launch_bounds__(256) void agg_kernel(const float* __restrict__ t,
                                                  const float* __restrict__ bias,
                                                  const int* __restrict__ rp,
                                                  const long long* __restrict__ csr,
                                                  unsigned* __restrict__ hp, int n) {
    int local = threadIdx.x & 31;
    int j = blockIdx.x * 8 + (threadIdx.x >> 5);
    if (j >= n) return;
    int c4 = local * 4;
    int p0 = rp[j], p1 = rp[j + 1];
    float4 acc0 = make_float4(0.f, 0.f, 0.f, 0.f);
    float4 acc1 = make_float4(0.f, 0.f, 0.f, 0.f);
    float4 acc2 = make_float4(0.f, 0.f, 0.f, 0.f);
    float4 acc3 = make_float4(0.f, 0.f, 0.f, 0.f);
    int p = p0;
    for (; p + 4 <= p1; p += 4) {
        long long e0 = csr[p], e1 = csr[p + 1], e2 = csr[p + 2], e3 = csr[p + 3];
        float w0 = __int_as_float((int)(e0 >> 32));
        float w1 = __int_as_float((int)(e1 >> 32));
        float w2 = __int_as_float((int)(e2 >> 32));
        float w3 = __int_as_float((int)(e3 >> 32));
        float4 v0 = *(const float4*)&t[(size_t)((int)e0) * 128 + c4];
        float4 v1 = *(const float4*)&t[(size_t)((int)e1) * 128 + c4];
        float4 v2 = *(const float4*)&t[(size_t)((int)e2) * 128 + c4];
        float4 v3 = *(const float4*)&t[(size_t)((int)e3) * 128 + c4];
        acc0.x += w0 * v0.x; acc0.y += w0 * v0.y; acc0.z += w0 * v0.z; acc0.w += w0 * v0.w;
        acc1.x += w1 * v1.x; acc1.y += w1 * v1.y; acc1.z += w1 * v1.z; acc1.w += w1 * v1.w;
        acc2.x += w2 * v2.x; acc2.y += w2 * v2.y; acc2.z += w2 * v2.z; acc2.w += w2 * v2.w;
        acc3.x += w3 * v3.x; acc3.y += w3 * v3.y; acc3.z += w3 * v3.z; acc3.w += w3 * v3.w;
    }
    for (; p < p1; ++p) {
        long long e0 = csr[p];
        float w0 = __int_as_float((int)(e0 >> 32));
        float4 v0 = *(const float4*)&t[(size_t)((int)e0) * 128 + c4];
        acc0.x += w0 * v0.x; acc0.y += w0 * v0.y; acc0.z += w0 * v0.z; acc0.w += w0 * v0.w;
    }
    float4 b = *(const float4*)&bias[c4];
    float ox = fmaxf(acc0.x + acc1.x + acc2.x + acc3.x + b.x, 0.f);
    float oy = fmaxf(acc0.y + acc1.y + acc2.y + acc3.y + b.y, 0.f);
    float oz = fmaxf(acc0.z + acc1.z + acc2.z + acc3.z + b.z, 0.f);
    float ow = fmaxf(acc0.w + acc1.w + acc2.w + acc3.w + b.w, 0.f);
    uint4 st;
    st.x = packsplit(ox); st.y = packsplit(oy); st.z = packsplit(oz); st.w = packsplit(ow);
    *(uint4*)&hp[(size_t)j * 128 + c4] = st;
}

// ---------------- pooling + classifier (one block per graph, no atomics) ----------------

__global__ __launch_bounds__(256) void pool_kernel(const float* __restrict__ t,
                                                   const float* __restrict__ bfc,
                                                   const int* __restrict__ batch,
                                                   const float* __restrict__ Wlin,
                                                   const float* __restrict__ blin,
                                                   float* __restrict__ out, int n) {
    int g = blockIdx.x;
    int tid = threadIdx.x;
    int lo = 0, hi = n;
    while (lo < hi) { int m = (lo + hi) >> 1; if (batch[m] < g) lo = m + 1; else hi = m; }
    int start = lo;
    lo = start; hi = n;
    while (lo < hi) { int m = (lo + hi) >> 1; if (batch[m] < g + 1) lo = m + 1; else hi = m; }
    int end = lo;

    int lane = tid & 31, sub = tid >> 5;
    int c4 = lane * 4;
    float4 bv = *(const float4*)&bfc[c4];
    float sx = 0.f, sy = 0.f, sz = 0.f, sw = 0.f;
    for (int j = start + sub; j < end; j += 8) {
        float4 v = *(const float4*)&t[(size_t)j * 128 + c4];
        sx += fmaxf(v.x + bv.x, 0.f);
        sy += fmaxf(v.y + bv.y, 0.f);
        sz += fmaxf(v.z + bv.z, 0.f);
        sw += fmaxf(v.w + bv.w, 0.f);
    }
    __shared__ float red[8][128];
    red[sub][c4] = sx; red[sub][c4 + 1] = sy; red[sub][c4 + 2] = sz; red[sub][c4 + 3] = sw;
    __syncthreads();
    __shared__ float pooled[128];
    if (tid < 128) {
        float s = 0.f;
        #pragma unroll
        for (int k = 0; k < 8; ++k) s += red[k][tid];
        float pv = s / fmaxf((float)(end - start), 1.f);
        pooled[tid] = pv;
        out[1280 + g * 128 + tid] = pv;
    }
    __syncthreads();
    if (tid < 10) {
        float a = blin[tid];
        for (int k = 0; k < 128; ++k) a += pooled[k] * Wlin[k * 10 + tid];
        out[g * 10 + tid] = a;
    }
}

// ---------------- launch ----------------

extern "C" void kernel_launch(void* const* d_in, const int* in_sizes, int n_in,
                              void* d_out, int out_size, void* d_ws, size_t ws_size,
                              hipStream_t stream) {
    const float* x     = (const float*)d_in[0];
    const int*   ei    = (const int*)d_in[1];
    const int*   batch = (const int*)d_in[2];
    const float* Wl[6] = {(const float*)d_in[3], (const float*)d_in[5], (const float*)d_in[7],
                          (const float*)d_in[9], (const float*)d_in[11], (const float*)d_in[13]};
    const float* bl[6] = {(const float*)d_in[4], (const float*)d_in[6], (const float*)d_in[8],
                          (const float*)d_in[10], (const float*)d_in[12], (const float*)d_in[14]};
    const float* Wlin = (const float*)d_in[15];
    const float* blin = (const float*)d_in[16];

    const int N = in_sizes[2];        // 50000
    const int E = in_sizes[1] / 2;    // 600000
    (void)n_in; (void)out_size; (void)ws_size;

    char* p = (char*)d_ws;
    auto carve = [&](size_t bytes) { void* r = (void*)p; p += (bytes + 255) & ~(size_t)255; return r; };
    float*          t      = (float*)carve((size_t)N * 128 * 4);      // fp32 gemm output
    unsigned*       hp     = (unsigned*)carve((size_t)N * 128 * 4);   // packed agg output
    int*            degi   = (int*)carve((size_t)N * 4);
    float*          dinv   = (float*)carve((size_t)N * 4);
    int*            rp     = (int*)carve((size_t)(N + 1) * 4);
    int*            cursor = (int*)carve((size_t)N * 4);
    long long*      csr    = (long long*)carve((size_t)(E + N) * 8);
    int*            bsum   = (int*)carve(256 * 4);
    unsigned short* wth    = (unsigned short*)carve(6 * 16384 * 2);
    unsigned short* wtl    = (unsigned short*)carve(6 * 16384 * 2);

    int gN = (N + 255) / 256;
    hipMemsetAsync(degi, 0, (size_t)N * 4, stream);
    count_kernel<<<(E + 255) / 256, 256, 0, stream>>>(ei, degi, E);
    scan_bsum_kernel<<<gN, 256, 0, stream>>>(degi, dinv, bsum, N);
    scan_emit_kernel<<<gN, 256, 0, stream>>>(degi, bsum, rp, cursor, N, gN);
    fill_kernel<<<(E + N + 255) / 256, 256, 0, stream>>>(ei, dinv, cursor, csr, E, N);
    packw_kernel<<<dim3(64, 6), 256, 0, stream>>>(Wl[0], Wl[1], Wl[2], Wl[3], Wl[4], Wl[5],
                                                  wth, wtl);

    int gGemm = (N + 127) / 128;
    int gAgg  = (N + 7) / 8;
    gemm0_kernel<<<gGemm, 512, 0, stream>>>(x, wth, wtl, t, N);
    agg_kernel<<<gAgg, 256, 0, stream>>>(t, bl[0], rp, csr, hp, N);
    for (int l = 1; l < 5; ++l) {
        gemm_kernel<<<gGemm, 512, 0, stream>>>(hp, wth + l * 16384, wtl + l * 16384, t, N);
        agg_kernel<<<gAgg, 256, 0, stream>>>(t, bl[l], rp, csr, hp, N);
    }
    gemm_kernel<<<gGemm, 512, 0, stream>>>(hp, wth + 5 * 16384, wtl + 5 * 16384, t, N);
    pool_kernel<<<128, 256, 0, stream>>>(t, bl[5], batch, Wlin, blin, (float*)d_out, N);
}